// Round 7
// baseline (781.841 us; speedup 1.0000x reference)
//
#include <hip/hip_runtime.h>
#include <cstdint>

// Problem dims (fixed by reference)
#define BB 4
#define SS 2048
#define HH 1024
#define FF 4096
#define MM (BB * SS)   // 8192 tokens

typedef __attribute__((ext_vector_type(8))) short bf16x8;
typedef __attribute__((ext_vector_type(4))) float f32x4;

__device__ __forceinline__ unsigned short f2b(float f) {
  union { float f; unsigned u; } v; v.f = f;
  unsigned r = v.u + 0x7FFFu + ((v.u >> 16) & 1u);   // round-nearest-even
  return (unsigned short)(r >> 16);
}
__device__ __forceinline__ float b2f(unsigned short u) {
  union { unsigned u; float f; } v; v.u = ((unsigned)u) << 16; return v.f;
}

// ---------- elementwise fp32 -> bf16 ----------
__global__ __launch_bounds__(256) void conv_f2b_kernel(
    const float* __restrict__ in, unsigned short* __restrict__ out, long n4) {
  long i = (long)blockIdx.x * 256 + threadIdx.x;
  if (i >= n4) return;
  const float4 f = ((const float4*)in)[i];
  ushort4 o;
  o.x = f2b(f.x); o.y = f2b(f.y); o.z = f2b(f.z); o.w = f2b(f.w);
  ((ushort4*)out)[i] = o;
}

// ---------- transpose fp32 [R,C] -> bf16 [C,R] ----------
__global__ __launch_bounds__(256) void transpose_f2b_kernel(
    const float* __restrict__ in, unsigned short* __restrict__ out, int R, int C) {
  __shared__ float t[32][33];
  int bc = blockIdx.x * 32;
  int br = blockIdx.y * 32;
  int x = threadIdx.x;   // 0..31
  int y0 = threadIdx.y;  // 0..7
#pragma unroll
  for (int yy = y0; yy < 32; yy += 8)
    t[yy][x] = in[(long)(br + yy) * C + bc + x];
  __syncthreads();
#pragma unroll
  for (int yy = y0; yy < 32; yy += 8)
    out[(long)(bc + yy) * R + br + x] = f2b(t[x][yy]);
}

// ---------- transpose bf16 [R,C] slice (ld_in given) -> bf16 [C,R] ----------
__global__ __launch_bounds__(256) void transpose_b2b_kernel(
    const unsigned short* __restrict__ in, long ldin,
    unsigned short* __restrict__ out, int R, int C) {
  __shared__ unsigned short t[32][33];
  int bc = blockIdx.x * 32;
  int br = blockIdx.y * 32;
  int x = threadIdx.x;
  int y0 = threadIdx.y;
#pragma unroll
  for (int yy = y0; yy < 32; yy += 8)
    t[yy][x] = in[(long)(br + yy) * ldin + bc + x];
  __syncthreads();
#pragma unroll
  for (int yy = y0; yy < 32; yy += 8)
    out[(long)(bc + yy) * R + br + x] = t[x][yy];
}

// ---------- concat 3 bias vectors [HH] -> [3*HH] ----------
__global__ __launch_bounds__(256) void concat3_kernel(
    const float* __restrict__ a, const float* __restrict__ b,
    const float* __restrict__ c, float* __restrict__ o) {
  int i = blockIdx.x * 256 + threadIdx.x;   // 0..3071
  float v = (i < HH) ? a[i] : (i < 2 * HH) ? b[i - HH] : c[i - 2 * HH];
  o[i] = v;
}

// ---------- bf16 MFMA GEMM: C[M,N] = A[M,K] * B[N,K]^T ----------
// 128x128 tile, 4 waves 2x2, each wave 64x64 via 4x4 of 16x16x32 MFMA.
// BK=64, register-prefetch pipeline (round 7):
//   iter k: [global loads k+64 -> VGPRs] [ds_read+MFMA on LDS(k)]
//           [barrier] [ds_write regs -> LDS] [barrier]
// The vmcnt wait for the prefetch lands AFTER the MFMA block, so HBM/L2
// latency (~200-900 cyc) is hidden by ~1200 cyc of MFMA per CU-iter.
// ds_write is per-lane addressed (no gld16 wave-uniform constraint), so we
// get BOTH coalesced global loads AND a phase-conflict-free LDS layout:
//   slot(row,c) = (row>>4)*1024 + (row&15)*64 + ((c ^ (row&7))*8)  [shorts]
// - global map: chunk g = tid+256j -> row g>>3, c g&7: 8 consecutive threads
//   sweep one contiguous 128 B row segment (coalescer-ideal).
// - ds_write: per 8 lanes, groups c^(row&7) cover all 8 bank-groups once.
// - ds_read (lane l, sub-k ks): row l&15, c = ks*4+(l>>4): per 16-lane phase
//   each bank-group hit exactly 2x (2-way is free, m136). [round 5/6's
//   f=row&3 left 4 lanes/group per phase -> the persistent 2^23 conflicts]
// OUT_MODE: 0 = fp32 out, 1 = bf16 out, 2 = fp32 out + bf16 secondary (C2)
template <int OUT_MODE, int RELU, int HAS_BIAS, int HAS_RES>
__device__ __forceinline__ void gemm_bt_body(
    const unsigned short* __restrict__ A, long lda, long sA,
    const unsigned short* __restrict__ Bm, long ldb, long sB,
    void* __restrict__ Cm, long ldc, long sC,
    unsigned short* __restrict__ C2,
    const float* __restrict__ bias,
    const float* __restrict__ res, long ldr,
    float scale, int K) {
  __shared__ unsigned short As[128 * 64];   // 16 KB, swizzled layout (above)
  __shared__ unsigned short Bs[128 * 64];
  const int tid = threadIdx.x;
  const int lane = tid & 63;
  const int wave = tid >> 6;
  const long bm = (long)blockIdx.y * 128;
  const long bn = (long)blockIdx.x * 128;
  const int z = blockIdx.z;

  // staging maps: 4 chunks per thread for A and for B
  long aoff[4], boff[4];
  int slot[4];
#pragma unroll
  for (int j = 0; j < 4; ++j) {
    const int g = tid + 256 * j;
    const int row = g >> 3, c = g & 7;
    aoff[j] = (long)row * lda + c * 8;
    boff[j] = (long)row * ldb + c * 8;
    slot[j] = (row >> 4) * 1024 + (row & 15) * 64 + ((c ^ (row & 7)) * 8);
  }
  const unsigned short* Ab0 = A + (long)z * sA + bm * lda;
  const unsigned short* Bb0 = Bm + (long)z * sB + bn * ldb;

  f32x4 acc[4][4];
#pragma unroll
  for (int i = 0; i < 4; ++i)
#pragma unroll
    for (int j = 0; j < 4; ++j) acc[i][j] = (f32x4){0.f, 0.f, 0.f, 0.f};

  // prologue: stage tile 0
  bf16x8 areg[4], breg[4];
#pragma unroll
  for (int j = 0; j < 4; ++j) {
    areg[j] = *(const bf16x8*)(Ab0 + aoff[j]);
    breg[j] = *(const bf16x8*)(Bb0 + boff[j]);
  }
#pragma unroll
  for (int j = 0; j < 4; ++j) {
    *(bf16x8*)&As[slot[j]] = areg[j];
    *(bf16x8*)&Bs[slot[j]] = breg[j];
  }
  __syncthreads();

  const int aw = (wave >> 1) * 4;   // A window base (16-row windows)
  const int bw = (wave & 1) * 4;
  const int fr = lane & 15;
  const int fx = lane & 7;
  const int fq = lane >> 4;

  for (int k0 = 0; k0 < K; k0 += 64) {
    const bool more = (k0 + 64) < K;
    if (more) {
#pragma unroll
      for (int j = 0; j < 4; ++j) {
        areg[j] = *(const bf16x8*)(Ab0 + aoff[j] + k0 + 64);
        breg[j] = *(const bf16x8*)(Bb0 + boff[j] + k0 + 64);
      }
    }
#pragma unroll
    for (int ks = 0; ks < 2; ++ks) {
      bf16x8 af[4], bfr[4];
      const int co = ((ks * 4 + fq) ^ fx) * 8;
#pragma unroll
      for (int i = 0; i < 4; ++i)
        af[i] = *(const bf16x8*)&As[(aw + i) * 1024 + fr * 64 + co];
#pragma unroll
      for (int i = 0; i < 4; ++i)
        bfr[i] = *(const bf16x8*)&Bs[(bw + i) * 1024 + fr * 64 + co];
#pragma unroll
      for (int mi = 0; mi < 4; ++mi)
#pragma unroll
        for (int ni = 0; ni < 4; ++ni)
          acc[mi][ni] = __builtin_amdgcn_mfma_f32_16x16x32_bf16(af[mi], bfr[ni], acc[mi][ni], 0, 0, 0);
    }
    __syncthreads();               // all LDS reads of tile k done
    if (more) {
#pragma unroll
      for (int j = 0; j < 4; ++j) {
        *(bf16x8*)&As[slot[j]] = areg[j];
        *(bf16x8*)&Bs[slot[j]] = breg[j];
      }
      __syncthreads();             // tile k+64 visible
    }
  }

  // epilogue: C/D layout col=lane&15, row=(lane>>4)*4+reg (m89-verified)
  const int mo = (wave >> 1) * 64;
  const int no = (wave & 1) * 64;
  const long crow = bm + mo + ((lane >> 4) * 4);
  const long ccol = bn + no + (lane & 15);
#pragma unroll
  for (int mi = 0; mi < 4; ++mi) {
#pragma unroll
    for (int ni = 0; ni < 4; ++ni) {
      const long col = ccol + ni * 16;
      const float bv = HAS_BIAS ? bias[col] : 0.f;
#pragma unroll
      for (int r = 0; r < 4; ++r) {
        const long row = crow + mi * 16 + r;
        float v = acc[mi][ni][r] * scale + bv;
        if (HAS_RES) v += res[row * ldr + col];
        if (RELU) v = fmaxf(v, 0.f);
        const long idx = (long)z * sC + row * ldc + col;
        if (OUT_MODE == 0 || OUT_MODE == 2) ((float*)Cm)[idx] = v;
        if (OUT_MODE == 1) ((unsigned short*)Cm)[idx] = f2b(v);
        if (OUT_MODE == 2) C2[idx] = f2b(v);
      }
    }
  }
}

#define GEMM_KERNEL(NAME, OM, RELU, HB, HR)                                  \
  __global__ __launch_bounds__(256) void NAME(                               \
      const unsigned short* __restrict__ A, long lda, long sA,               \
      const unsigned short* __restrict__ Bm, long ldb, long sB,              \
      void* __restrict__ Cm, long ldc, long sC,                              \
      unsigned short* __restrict__ C2, const float* __restrict__ bias,       \
      const float* __restrict__ res, long ldr, float scale, int K) {         \
    gemm_bt_body<OM, RELU, HB, HR>(A, lda, sA, Bm, ldb, sB, Cm, ldc, sC,     \
                                   C2, bias, res, ldr, scale, K);            \
  }
GEMM_KERNEL(gemm_qkv,  1, 0, 1, 0)
GEMM_KERNEL(gemm_qk,   1, 0, 0, 1)   // bf16 scores, mask fused as residual
GEMM_KERNEL(gemm_av,   2, 0, 0, 0)
GEMM_KERNEL(gemm_ffn1, 1, 1, 1, 0)
GEMM_KERNEL(gemm_ffn2, 0, 0, 1, 1)

// ---------- row softmax over S, bf16 in (mask pre-added) -> bf16 out ----------
__global__ __launch_bounds__(256) void softmax_kernel(
    const unsigned short* __restrict__ Sb, unsigned short* __restrict__ Ab) {
  const long row = blockIdx.x;          // 0..MM-1
  const int tid = threadIdx.x;
  const unsigned short* sr = Sb + row * SS + tid * 8;
  bf16x8 sv = *(const bf16x8*)sr;
  float v[8];
  float mx = -1e30f;
#pragma unroll
  for (int i = 0; i < 8; ++i) {
    v[i] = b2f((unsigned short)sv[i]);
    mx = fmaxf(mx, v[i]);
  }
#pragma unroll
  for (int off = 32; off > 0; off >>= 1) mx = fmaxf(mx, __shfl_xor(mx, off, 64));
  __shared__ float rm[4], rs[4];
  if ((tid & 63) == 0) rm[tid >> 6] = mx;
  __syncthreads();
  mx = fmaxf(fmaxf(rm[0], rm[1]), fmaxf(rm[2], rm[3]));
  float sum = 0.f;
#pragma unroll
  for (int i = 0; i < 8; ++i) { v[i] = __expf(v[i] - mx); sum += v[i]; }
#pragma unroll
  for (int off = 32; off > 0; off >>= 1) sum += __shfl_xor(sum, off, 64);
  if ((tid & 63) == 0) rs[tid >> 6] = sum;
  __syncthreads();
  sum = rs[0] + rs[1] + rs[2] + rs[3];
  const float inv = 1.f / sum;
  bf16x8 ov;
#pragma unroll
  for (int i = 0; i < 8; ++i) ov[i] = (short)f2b(v[i] * inv);
  *(bf16x8*)(Ab + row * SS + tid * 8) = ov;
}

// ---------- in-place LayerNorm over H=1024 ----------
__global__ __launch_bounds__(256) void layernorm_kernel(
    float* __restrict__ Y, const float* __restrict__ g, const float* __restrict__ b) {
  const long row = blockIdx.x;
  float* y = Y + row * HH;
  const int tid = threadIdx.x;
  float v[4];
  float s = 0.f, ss = 0.f;
#pragma unroll
  for (int i = 0; i < 4; ++i) {
    v[i] = y[tid + i * 256];
    s += v[i]; ss += v[i] * v[i];
  }
#pragma unroll
  for (int off = 32; off > 0; off >>= 1) {
    s += __shfl_xor(s, off, 64);
    ss += __shfl_xor(ss, off, 64);
  }
  __shared__ float r1[4], r2[4];
  if ((tid & 63) == 0) { r1[tid >> 6] = s; r2[tid >> 6] = ss; }
  __syncthreads();
  s = r1[0] + r1[1] + r1[2] + r1[3];
  ss = r2[0] + r2[1] + r2[2] + r2[3];
  const float mu = s * (1.f / HH);
  const float var = ss * (1.f / HH) - mu * mu;
  const float rinv = rsqrtf(var + 1e-5f);
#pragma unroll
  for (int i = 0; i < 4; ++i) {
    int c = tid + i * 256;
    y[c] = (v[i] - mu) * rinv * g[c] + b[c];
  }
}

extern "C" void kernel_launch(void* const* d_in, const int* in_sizes, int n_in,
                              void* d_out, int out_size, void* d_ws, size_t ws_size,
                              hipStream_t stream) {
  (void)in_sizes; (void)n_in; (void)out_size; (void)ws_size;
  const float* x     = (const float*)d_in[0];
  const float* mask  = (const float*)d_in[1];
  const float* qW    = (const float*)d_in[2];
  const float* qb    = (const float*)d_in[3];
  const float* kW    = (const float*)d_in[4];
  const float* kb    = (const float*)d_in[5];
  const float* vW    = (const float*)d_in[6];
  const float* vb    = (const float*)d_in[7];
  const float* w1    = (const float*)d_in[8];
  const float* b1    = (const float*)d_in[9];
  const float* w2    = (const float*)d_in[10];
  const float* b2    = (const float*)d_in[11];
  const float* gamma = (const float*)d_in[12];
  const float* beta  = (const float*)d_in[13];
  float* out = (float*)d_out;

  char* ws = (char*)d_ws;
  size_t o = 0;
  auto alloc = [&](size_t bytes) { void* p = ws + o; o += (bytes + 255) & ~(size_t)255; return p; };
  unsigned short* Wqkv = (unsigned short*)alloc((size_t)3 * HH * HH * 2); // [3072][1024] (N,K) bf16
  unsigned short* w1t  = (unsigned short*)alloc((size_t)FF * HH * 2);     // [F][H]
  unsigned short* w2t  = (unsigned short*)alloc((size_t)HH * FF * 2);     // [H][F]
  float*          qkvb = (float*)alloc((size_t)3 * HH * 4);               // concat bias
  unsigned short* xb   = (unsigned short*)alloc((size_t)MM * HH * 2);     // x bf16
  unsigned short* QKVb = (unsigned short*)alloc((size_t)MM * 3 * HH * 2); // [M,3072] bf16
  unsigned short* Vt   = (unsigned short*)alloc((size_t)HH * MM * 2);     // [H][M] V^T bf16
  float*          attnf= (float*)alloc((size_t)MM * HH * 4);              // attn fp32 (residual)
  unsigned short* attnb= (unsigned short*)alloc((size_t)MM * HH * 2);     // attn bf16
  unsigned short* Sb   = (unsigned short*)alloc((size_t)BB * SS * SS * 4);// scores bf16 (over-alloc; tail reused as hb)
  unsigned short* Ab   = (unsigned short*)alloc((size_t)BB * SS * SS * 2);
  unsigned short* hb   = Sb + (size_t)BB * SS * SS;  // [M,F] bf16; Sb dead by FFN1 time

  const dim3 tb(32, 8);

  // 1. x -> bf16
  conv_f2b_kernel<<<MM * HH / 1024, 256, 0, stream>>>(x, xb, (long)MM * HH / 4);
  // 2. weight transposes (fp32 [K,N] -> bf16 [N,K]); QKV concatenated along N
  transpose_f2b_kernel<<<dim3(HH / 32, HH / 32), tb, 0, stream>>>(qW, Wqkv, HH, HH);
  transpose_f2b_kernel<<<dim3(HH / 32, HH / 32), tb, 0, stream>>>(kW, Wqkv + (size_t)HH * HH, HH, HH);
  transpose_f2b_kernel<<<dim3(HH / 32, HH / 32), tb, 0, stream>>>(vW, Wqkv + (size_t)2 * HH * HH, HH, HH);
  transpose_f2b_kernel<<<dim3(FF / 32, HH / 32), tb, 0, stream>>>(w1, w1t, HH, FF);
  transpose_f2b_kernel<<<dim3(HH / 32, FF / 32), tb, 0, stream>>>(w2, w2t, FF, HH);
  concat3_kernel<<<12, 256, 0, stream>>>(qb, kb, vb, qkvb);
  // 3. QKV = x * Wqkv^T + b, single GEMM, bf16 out [M,3072]
  gemm_qkv<<<dim3(3 * HH / 128, MM / 128, 1), 256, 0, stream>>>(
      xb, HH, 0, Wqkv, HH, 0, QKVb, 3 * HH, 0, nullptr, qkvb, nullptr, 0, 1.f, HH);
  // 4. V^T (bf16 [M,1024] slice of QKVb -> bf16 [1024,M])
  transpose_b2b_kernel<<<dim3(HH / 32, MM / 32), tb, 0, stream>>>(
      QKVb + 2 * HH, 3 * HH, Vt, MM, HH);
  // 5. S = Q K^T / sqrt(H) + mask, batched over BB, bf16 out
  gemm_qk<<<dim3(SS / 128, SS / 128, BB), 256, 0, stream>>>(
      QKVb, 3 * HH, (long)SS * 3 * HH, QKVb + HH, 3 * HH, (long)SS * 3 * HH,
      Sb, SS, (long)SS * SS, nullptr, nullptr, mask, SS, 0.03125f, HH);
  // 6. A = softmax(S) -> bf16
  softmax_kernel<<<MM, 256, 0, stream>>>(Sb, Ab);
  // 7. attn = A V, batched; fp32 + bf16 dual output
  gemm_av<<<dim3(HH / 128, SS / 128, BB), 256, 0, stream>>>(
      Ab, SS, (long)SS * SS, Vt, MM, SS, attnf, HH, (long)SS * HH,
      attnb, nullptr, nullptr, 0, 1.f, SS);
  // 8. h = relu(attn w1 + b1) -> bf16
  gemm_ffn1<<<dim3(FF / 128, MM / 128, 1), 256, 0, stream>>>(
      attnb, HH, 0, w1t, HH, 0, hb, FF, 0, nullptr, b1, nullptr, 0, 1.f, HH);
  // 9. y = attn + h w2 + b2 -> fp32 out
  gemm_ffn2<<<dim3(HH / 128, MM / 128, 1), 256, 0, stream>>>(
      hb, FF, 0, w2t, FF, 0, out, HH, 0, nullptr, b2, attnf, HH, 1.f, FF);
  // 10. LayerNorm in place
  layernorm_kernel<<<MM, 256, 0, stream>>>(out, gamma, beta);
}

// Round 8
// 579.048 us; speedup vs baseline: 1.3502x; 1.3502x over previous
//
#include <hip/hip_runtime.h>
#include <cstdint>

// Problem dims (fixed by reference)
#define BB 4
#define SS 2048
#define HH 1024
#define FF 4096
#define MM (BB * SS)   // 8192 tokens

typedef __attribute__((ext_vector_type(8))) short bf16x8;
typedef __attribute__((ext_vector_type(4))) float f32x4;

__device__ __forceinline__ unsigned short f2b(float f) {
  union { float f; unsigned u; } v; v.f = f;
  unsigned r = v.u + 0x7FFFu + ((v.u >> 16) & 1u);   // round-nearest-even
  return (unsigned short)(r >> 16);
}
__device__ __forceinline__ float b2f(unsigned short u) {
  union { unsigned u; float f; } v; v.u = ((unsigned)u) << 16; return v.f;
}

__device__ __forceinline__ void gld16(const void* g, void* l) {
  __builtin_amdgcn_global_load_lds(
      (const __attribute__((address_space(1))) void*)g,
      (__attribute__((address_space(3))) void*)l, 16, 0, 0);
}

// ---------- elementwise fp32 -> bf16 ----------
__global__ __launch_bounds__(256) void conv_f2b_kernel(
    const float* __restrict__ in, unsigned short* __restrict__ out, long n4) {
  long i = (long)blockIdx.x * 256 + threadIdx.x;
  if (i >= n4) return;
  const float4 f = ((const float4*)in)[i];
  ushort4 o;
  o.x = f2b(f.x); o.y = f2b(f.y); o.z = f2b(f.z); o.w = f2b(f.w);
  ((ushort4*)out)[i] = o;
}

// ---------- transpose fp32 [R,C] -> bf16 [C,R] ----------
__global__ __launch_bounds__(256) void transpose_f2b_kernel(
    const float* __restrict__ in, unsigned short* __restrict__ out, int R, int C) {
  __shared__ float t[32][33];
  int bc = blockIdx.x * 32;
  int br = blockIdx.y * 32;
  int x = threadIdx.x;   // 0..31
  int y0 = threadIdx.y;  // 0..7
#pragma unroll
  for (int yy = y0; yy < 32; yy += 8)
    t[yy][x] = in[(long)(br + yy) * C + bc + x];
  __syncthreads();
#pragma unroll
  for (int yy = y0; yy < 32; yy += 8)
    out[(long)(bc + yy) * R + br + x] = f2b(t[x][yy]);
}

// ---------- transpose bf16 [R,C] slice (ld_in given) -> bf16 [C,R] ----------
__global__ __launch_bounds__(256) void transpose_b2b_kernel(
    const unsigned short* __restrict__ in, long ldin,
    unsigned short* __restrict__ out, int R, int C) {
  __shared__ unsigned short t[32][33];
  int bc = blockIdx.x * 32;
  int br = blockIdx.y * 32;
  int x = threadIdx.x;
  int y0 = threadIdx.y;
#pragma unroll
  for (int yy = y0; yy < 32; yy += 8)
    t[yy][x] = in[(long)(br + yy) * ldin + bc + x];
  __syncthreads();
#pragma unroll
  for (int yy = y0; yy < 32; yy += 8)
    out[(long)(bc + yy) * R + br + x] = t[x][yy];
}

// ---------- concat 3 bias vectors [HH] -> [3*HH] ----------
__global__ __launch_bounds__(256) void concat3_kernel(
    const float* __restrict__ a, const float* __restrict__ b,
    const float* __restrict__ c, float* __restrict__ o) {
  int i = blockIdx.x * 256 + threadIdx.x;   // 0..3071
  float v = (i < HH) ? a[i] : (i < 2 * HH) ? b[i - HH] : c[i - 2 * HH];
  o[i] = v;
}

// ---------- bf16 MFMA GEMM: C[M,N] = A[M,K] * B[N,K]^T ----------
// 128xBN tile (BN=128 or 64), 4 waves 2x2, wave = 64M x (BN/2)N via
// 4 x (BN/32) of 16x16x32 MFMA. BK=64 as two BK=32 sub-tiles, gld16 staging
// (round-6 structure — round-7's register prefetch regressed: per-wave MFMA
// (~155 cyc) can't cover load latency; gld16 + inter-wave overlap can).
//
// LDS swizzle (round 8): slot(row, c_stored) = row*64B + c_stored*16B,
// c_stored = c_global ^ f(row), f(row) = (row>>1)&3   [bits 1-2, NOT row&3].
// - staging lane t: row=t>>2, c_global=(t&3)^((t>>3)&3): quad covers one
//   contiguous 64 B segment (coalescer-ideal); gld16 LDS write is
//   lane-linear (conflict-free by construction).
// - ds_read phase p (lanes 16p+i): group = (4i + p^((i>>1)&3)) mod 8:
//   even i -> groups 0..3 twice, odd i -> 4..7 twice => 2-way = free (m136).
//   [round-6's f=row&3 gave 4 lanes on 4 groups per phase -> 8.4M conflicts]
// OUT_MODE: 0 = fp32 out, 1 = bf16 out, 2 = fp32 out + bf16 secondary (C2)
template <int OUT_MODE, int RELU, int HAS_BIAS, int HAS_RES, int BN>
__device__ __forceinline__ void gemm_bt_body(
    const unsigned short* __restrict__ A, long lda, long sA,
    const unsigned short* __restrict__ Bm, long ldb, long sB,
    void* __restrict__ Cm, long ldc, long sC,
    unsigned short* __restrict__ C2,
    const float* __restrict__ bias,
    const float* __restrict__ res, long ldr,
    float scale, int K) {
  constexpr int NW = BN / 32;       // n-fragments per wave (4 or 2)
  constexpr int BSUB = BN * 32;     // Bs shorts per BK=32 sub-tile
  __shared__ unsigned short As[2 * 128 * 32];
  __shared__ unsigned short Bs[2 * BSUB];
  const int tid = threadIdx.x;
  const int lane = tid & 63;
  const int wave = tid >> 6;
  const long bm = (long)blockIdx.y * 128;
  const long bn = (long)blockIdx.x * BN;
  const int z = blockIdx.z;

  // staging: row = tid>>2 (quads sweep contiguous 64B), XOR'd chunk
  const long srow = tid >> 2;                              // 0..63
  const long schunk = (long)((tid & 3) ^ ((tid >> 3) & 3));
  const unsigned short* Ap = A + (long)z * sA + (bm + srow) * lda + schunk * 8;
  const unsigned short* Bp = Bm + (long)z * sB + (bn + srow) * ldb + schunk * 8;
  unsigned short* asd = As + tid * 8;
  unsigned short* bsd = Bs + tid * 8;
  const long a64 = 64 * lda;   // f(row+64)==f(row): bits 1-2 unchanged
  const long b64 = 64 * ldb;

  f32x4 acc[4][NW];
#pragma unroll
  for (int i = 0; i < 4; ++i)
#pragma unroll
    for (int j = 0; j < NW; ++j) acc[i][j] = (f32x4){0.f, 0.f, 0.f, 0.f};

  const int mo = (wave >> 1) * 64;
  const int no = (wave & 1) * (BN / 2);
  const int fr = lane & 15;                              // fragment row
  const int fc = (((lane >> 4) ^ ((lane >> 1) & 3))) * 8; // stored-chunk off

  for (int k0 = 0; k0 < K; k0 += 64) {
    __syncthreads();
    // A sub-tile 0 (k-cols [k0,k0+32)) and 1 ([k0+32,k0+64))
    gld16(Ap + k0, asd);
    gld16(Ap + a64 + k0, asd + 2048);
    gld16(Ap + k0 + 32, asd + 4096);
    gld16(Ap + a64 + k0 + 32, asd + 6144);
    // B sub-tiles (BN=64: rows 0..63 only, one gld16 each)
    gld16(Bp + k0, bsd);
    if (BN == 128) gld16(Bp + b64 + k0, bsd + 2048);
    gld16(Bp + k0 + 32, bsd + BSUB);
    if (BN == 128) gld16(Bp + b64 + k0 + 32, bsd + BSUB + 2048);
    __syncthreads();
#pragma unroll
    for (int ks = 0; ks < 2; ++ks) {
      bf16x8 af[4], bfr[NW];
#pragma unroll
      for (int i = 0; i < 4; ++i)
        af[i] = *(const bf16x8*)&As[ks * 4096 + (mo + i * 16 + fr) * 32 + fc];
#pragma unroll
      for (int i = 0; i < NW; ++i)
        bfr[i] = *(const bf16x8*)&Bs[ks * BSUB + (no + i * 16 + fr) * 32 + fc];
#pragma unroll
      for (int mi = 0; mi < 4; ++mi)
#pragma unroll
        for (int ni = 0; ni < NW; ++ni)
          acc[mi][ni] = __builtin_amdgcn_mfma_f32_16x16x32_bf16(af[mi], bfr[ni], acc[mi][ni], 0, 0, 0);
    }
  }

  // epilogue: C/D layout col=lane&15, row=(lane>>4)*4+reg (m89-verified)
  const long crow = bm + mo + ((lane >> 4) * 4);
  const long ccol = bn + no + (lane & 15);
#pragma unroll
  for (int mi = 0; mi < 4; ++mi) {
#pragma unroll
    for (int ni = 0; ni < NW; ++ni) {
      const long col = ccol + ni * 16;
      const float bv = HAS_BIAS ? bias[col] : 0.f;
#pragma unroll
      for (int r = 0; r < 4; ++r) {
        const long row = crow + mi * 16 + r;
        float v = acc[mi][ni][r] * scale + bv;
        if (HAS_RES) v += res[row * ldr + col];
        if (RELU) v = fmaxf(v, 0.f);
        const long idx = (long)z * sC + row * ldc + col;
        if (OUT_MODE == 0 || OUT_MODE == 2) ((float*)Cm)[idx] = v;
        if (OUT_MODE == 1) ((unsigned short*)Cm)[idx] = f2b(v);
        if (OUT_MODE == 2) C2[idx] = f2b(v);
      }
    }
  }
}

#define GEMM_KERNEL(NAME, OM, RELU, HB, HR, BN)                              \
  __global__ __launch_bounds__(256) void NAME(                               \
      const unsigned short* __restrict__ A, long lda, long sA,               \
      const unsigned short* __restrict__ Bm, long ldb, long sB,              \
      void* __restrict__ Cm, long ldc, long sC,                              \
      unsigned short* __restrict__ C2, const float* __restrict__ bias,       \
      const float* __restrict__ res, long ldr, float scale, int K) {         \
    gemm_bt_body<OM, RELU, HB, HR, BN>(A, lda, sA, Bm, ldb, sB, Cm, ldc,     \
                                       sC, C2, bias, res, ldr, scale, K);    \
  }
GEMM_KERNEL(gemm_qkv,  1, 0, 1, 0, 128)
GEMM_KERNEL(gemm_qk,   1, 0, 0, 1, 128)   // bf16 scores, mask as residual
GEMM_KERNEL(gemm_av,   2, 0, 0, 0, 64)    // N=1024: BN=64 -> 1024 blocks
GEMM_KERNEL(gemm_ffn1, 1, 1, 1, 0, 128)
GEMM_KERNEL(gemm_ffn2, 0, 0, 1, 1, 64)    // N=1024: BN=64 -> 1024 blocks

// ---------- row softmax over S, bf16 in (mask pre-added) -> bf16 out ----------
__global__ __launch_bounds__(256) void softmax_kernel(
    const unsigned short* __restrict__ Sb, unsigned short* __restrict__ Ab) {
  const long row = blockIdx.x;          // 0..MM-1
  const int tid = threadIdx.x;
  const unsigned short* sr = Sb + row * SS + tid * 8;
  bf16x8 sv = *(const bf16x8*)sr;
  float v[8];
  float mx = -1e30f;
#pragma unroll
  for (int i = 0; i < 8; ++i) {
    v[i] = b2f((unsigned short)sv[i]);
    mx = fmaxf(mx, v[i]);
  }
#pragma unroll
  for (int off = 32; off > 0; off >>= 1) mx = fmaxf(mx, __shfl_xor(mx, off, 64));
  __shared__ float rm[4], rs[4];
  if ((tid & 63) == 0) rm[tid >> 6] = mx;
  __syncthreads();
  mx = fmaxf(fmaxf(rm[0], rm[1]), fmaxf(rm[2], rm[3]));
  float sum = 0.f;
#pragma unroll
  for (int i = 0; i < 8; ++i) { v[i] = __expf(v[i] - mx); sum += v[i]; }
#pragma unroll
  for (int off = 32; off > 0; off >>= 1) sum += __shfl_xor(sum, off, 64);
  if ((tid & 63) == 0) rs[tid >> 6] = sum;
  __syncthreads();
  sum = rs[0] + rs[1] + rs[2] + rs[3];
  const float inv = 1.f / sum;
  bf16x8 ov;
#pragma unroll
  for (int i = 0; i < 8; ++i) ov[i] = (short)f2b(v[i] * inv);
  *(bf16x8*)(Ab + row * SS + tid * 8) = ov;
}

// ---------- in-place LayerNorm over H=1024 ----------
__global__ __launch_bounds__(256) void layernorm_kernel(
    float* __restrict__ Y, const float* __restrict__ g, const float* __restrict__ b) {
  const long row = blockIdx.x;
  float* y = Y + row * HH;
  const int tid = threadIdx.x;
  float v[4];
  float s = 0.f, ss = 0.f;
#pragma unroll
  for (int i = 0; i < 4; ++i) {
    v[i] = y[tid + i * 256];
    s += v[i]; ss += v[i] * v[i];
  }
#pragma unroll
  for (int off = 32; off > 0; off >>= 1) {
    s += __shfl_xor(s, off, 64);
    ss += __shfl_xor(ss, off, 64);
  }
  __shared__ float r1[4], r2[4];
  if ((tid & 63) == 0) { r1[tid >> 6] = s; r2[tid >> 6] = ss; }
  __syncthreads();
  s = r1[0] + r1[1] + r1[2] + r1[3];
  ss = r2[0] + r2[1] + r2[2] + r2[3];
  const float mu = s * (1.f / HH);
  const float var = ss * (1.f / HH) - mu * mu;
  const float rinv = rsqrtf(var + 1e-5f);
#pragma unroll
  for (int i = 0; i < 4; ++i) {
    int c = tid + i * 256;
    y[c] = (v[i] - mu) * rinv * g[c] + b[c];
  }
}

extern "C" void kernel_launch(void* const* d_in, const int* in_sizes, int n_in,
                              void* d_out, int out_size, void* d_ws, size_t ws_size,
                              hipStream_t stream) {
  (void)in_sizes; (void)n_in; (void)out_size; (void)ws_size;
  const float* x     = (const float*)d_in[0];
  const float* mask  = (const float*)d_in[1];
  const float* qW    = (const float*)d_in[2];
  const float* qb    = (const float*)d_in[3];
  const float* kW    = (const float*)d_in[4];
  const float* kb    = (const float*)d_in[5];
  const float* vW    = (const float*)d_in[6];
  const float* vb    = (const float*)d_in[7];
  const float* w1    = (const float*)d_in[8];
  const float* b1    = (const float*)d_in[9];
  const float* w2    = (const float*)d_in[10];
  const float* b2    = (const float*)d_in[11];
  const float* gamma = (const float*)d_in[12];
  const float* beta  = (const float*)d_in[13];
  float* out = (float*)d_out;

  char* ws = (char*)d_ws;
  size_t o = 0;
  auto alloc = [&](size_t bytes) { void* p = ws + o; o += (bytes + 255) & ~(size_t)255; return p; };
  unsigned short* Wqkv = (unsigned short*)alloc((size_t)3 * HH * HH * 2); // [3072][1024] (N,K) bf16
  unsigned short* w1t  = (unsigned short*)alloc((size_t)FF * HH * 2);     // [F][H]
  unsigned short* w2t  = (unsigned short*)alloc((size_t)HH * FF * 2);     // [H][F]
  float*          qkvb = (float*)alloc((size_t)3 * HH * 4);               // concat bias
  unsigned short* xb   = (unsigned short*)alloc((size_t)MM * HH * 2);     // x bf16
  unsigned short* QKVb = (unsigned short*)alloc((size_t)MM * 3 * HH * 2); // [M,3072] bf16
  unsigned short* Vt   = (unsigned short*)alloc((size_t)HH * MM * 2);     // [H][M] V^T bf16
  float*          attnf= (float*)alloc((size_t)MM * HH * 4);              // attn fp32 (residual)
  unsigned short* attnb= (unsigned short*)alloc((size_t)MM * HH * 2);     // attn bf16
  unsigned short* Sb   = (unsigned short*)alloc((size_t)BB * SS * SS * 4);// scores bf16 (over-alloc; tail reused as hb)
  unsigned short* Ab   = (unsigned short*)alloc((size_t)BB * SS * SS * 2);
  unsigned short* hb   = Sb + (size_t)BB * SS * SS;  // [M,F] bf16; Sb dead by FFN1 time

  const dim3 tb(32, 8);

  // 1. x -> bf16
  conv_f2b_kernel<<<MM * HH / 1024, 256, 0, stream>>>(x, xb, (long)MM * HH / 4);
  // 2. weight transposes (fp32 [K,N] -> bf16 [N,K]); QKV concatenated along N
  transpose_f2b_kernel<<<dim3(HH / 32, HH / 32), tb, 0, stream>>>(qW, Wqkv, HH, HH);
  transpose_f2b_kernel<<<dim3(HH / 32, HH / 32), tb, 0, stream>>>(kW, Wqkv + (size_t)HH * HH, HH, HH);
  transpose_f2b_kernel<<<dim3(HH / 32, HH / 32), tb, 0, stream>>>(vW, Wqkv + (size_t)2 * HH * HH, HH, HH);
  transpose_f2b_kernel<<<dim3(FF / 32, HH / 32), tb, 0, stream>>>(w1, w1t, HH, FF);
  transpose_f2b_kernel<<<dim3(HH / 32, FF / 32), tb, 0, stream>>>(w2, w2t, FF, HH);
  concat3_kernel<<<12, 256, 0, stream>>>(qb, kb, vb, qkvb);
  // 3. QKV = x * Wqkv^T + b, single GEMM, bf16 out [M,3072]
  gemm_qkv<<<dim3(3 * HH / 128, MM / 128, 1), 256, 0, stream>>>(
      xb, HH, 0, Wqkv, HH, 0, QKVb, 3 * HH, 0, nullptr, qkvb, nullptr, 0, 1.f, HH);
  // 4. V^T (bf16 [M,1024] slice of QKVb -> bf16 [1024,M])
  transpose_b2b_kernel<<<dim3(HH / 32, MM / 32), tb, 0, stream>>>(
      QKVb + 2 * HH, 3 * HH, Vt, MM, HH);
  // 5. S = Q K^T / sqrt(H) + mask, batched over BB, bf16 out
  gemm_qk<<<dim3(SS / 128, SS / 128, BB), 256, 0, stream>>>(
      QKVb, 3 * HH, (long)SS * 3 * HH, QKVb + HH, 3 * HH, (long)SS * 3 * HH,
      Sb, SS, (long)SS * SS, nullptr, nullptr, mask, SS, 0.03125f, HH);
  // 6. A = softmax(S) -> bf16
  softmax_kernel<<<MM, 256, 0, stream>>>(Sb, Ab);
  // 7. attn = A V, batched; fp32 + bf16 dual output (BN=64)
  gemm_av<<<dim3(HH / 64, SS / 128, BB), 256, 0, stream>>>(
      Ab, SS, (long)SS * SS, Vt, MM, SS, attnf, HH, (long)SS * HH,
      attnb, nullptr, nullptr, 0, 1.f, SS);
  // 8. h = relu(attn w1 + b1) -> bf16
  gemm_ffn1<<<dim3(FF / 128, MM / 128, 1), 256, 0, stream>>>(
      attnb, HH, 0, w1t, HH, 0, hb, FF, 0, nullptr, b1, nullptr, 0, 1.f, HH);
  // 9. y = attn + h w2 + b2 -> fp32 out (BN=64)
  gemm_ffn2<<<dim3(HH / 64, MM / 128, 1), 256, 0, stream>>>(
      hb, FF, 0, w2t, FF, 0, out, HH, 0, nullptr, b2, attnf, HH, 1.f, FF);
  // 10. LayerNorm in place
  layernorm_kernel<<<MM, 256, 0, stream>>>(out, gamma, beta);
}